// Round 4
// baseline (311.886 us; speedup 1.0000x reference)
//
#include <hip/hip_runtime.h>

// ROI crop_and_resize: feature_map [8,64,64,256] f32 NHWC, rois [8,128,4] f32
// out [1024,14,14,256] f32.
//
// v5: DIAGNOSTIC ROUND - identical v4 kernel, launched TWICE (idempotent:
// pure function of inputs, second launch writes identical bytes).
// Purpose: four structurally different kernels (nt/plain stores, 3 XCD maps,
// 2x MLP) all land at 247-250.6 us total; the ROI kernel never appears in
// rocprof top-5 (all ~122us poison fills), so its duration is unobservable.
// Two surviving theories:
//   (a) dur_us = fill(123) + kernel(~122)  -> 85us of kernel headroom left
//   (b) dur_us = 2 fill-like ops + small kernel (stores absorbed by L2/L3)
//       -> harness floor, roofline
// Relaunching discriminates: (a) -> dur_us ~370 AND kernel enters top-5
// with visible FETCH/WRITE counters; (b) -> dur_us ~252-265, top-5 unchanged.

#define B_   8
#define H_   64
#define W_   64
#define C4_  64      // 256 channels / 4
#define NROI 128
#define CH_  14
#define CW_  14
// wave-task = (roi, i, j0) with j0 in [0,7): covers pixels (i,j0),(i,j0+7)
#define TASKS_PER_ROI (CH_ * 7)                 // 98
#define NTASKS (B_ * NROI * TASKS_PER_ROI)      // 100352
#define WAVES_PER_BLOCK 4
#define BLOCKS_TOTAL (NTASKS / WAVES_PER_BLOCK) // 25088

__global__ __launch_bounds__(256) void roi_crop_resize_kernel(
    const float4* __restrict__ fm,     // [8*64*64*64] float4
    const float*  __restrict__ rois,   // [1024*4]
    float4*       __restrict__ out)    // [200704*64] float4
{
    int tid = (int)threadIdx.x;
    int wt  = (int)blockIdx.x * WAVES_PER_BLOCK + (tid >> 6);  // wave-task id
    int cg  = tid & 63;                                        // channel group

    int n  = wt / TASKS_PER_ROI;            // roi index 0..1023
    int t  = wt - n * TASKS_PER_ROI;
    int i  = t / 7;                         // output row 0..13
    int j0 = t - i * 7;                     // first column 0..6  (pair: j0, j0+7)
    int b  = n >> 7;                        // batch

    const float* box = rois + n * 4;
    float y1 = box[0], x1 = box[1], y2 = box[2], x2 = box[3];

    const float Hm1 = (float)(H_ - 1);
    const float Wm1 = (float)(W_ - 1);

    float h_scale = (y2 - y1) * Hm1 / (float)(CH_ - 1);
    float w_scale = (x2 - x1) * Wm1 / (float)(CW_ - 1);

    // ---- shared y path (same i for both pixels) ----
    float in_y = y1 * Hm1 + (float)i * h_scale;
    bool  vy   = (in_y >= 0.0f) & (in_y <= Hm1);
    float fy   = floorf(in_y);
    float cy   = ceilf(in_y);
    int   ty   = (int)fminf(fmaxf(fy, 0.0f), Hm1);
    int   by   = (int)fminf(fmaxf(cy, 0.0f), Hm1);
    float yl   = in_y - fy;
    int rowT   = (b * H_ + ty) * W_;
    int rowB   = (b * H_ + by) * W_;

    // ---- x path, pixel A (j0) ----
    float in_xa = x1 * Wm1 + (float)j0 * w_scale;
    bool  vxa   = (in_xa >= 0.0f) & (in_xa <= Wm1);
    float fxa   = floorf(in_xa);
    float cxa   = ceilf(in_xa);
    int   lxa   = (int)fminf(fmaxf(fxa, 0.0f), Wm1);
    int   rxa   = (int)fminf(fmaxf(cxa, 0.0f), Wm1);
    float xla   = in_xa - fxa;

    // ---- x path, pixel B (j0+7) ----
    float in_xb = x1 * Wm1 + (float)(j0 + 7) * w_scale;
    bool  vxb   = (in_xb >= 0.0f) & (in_xb <= Wm1);
    float fxb   = floorf(in_xb);
    float cxb   = ceilf(in_xb);
    int   lxb   = (int)fminf(fmaxf(fxb, 0.0f), Wm1);
    int   rxb   = (int)fminf(fmaxf(cxb, 0.0f), Wm1);
    float xlb   = in_xb - fxb;

    // ---- 8 independent gather loads (max MLP) ----
    float4 aTL = fm[(rowT + lxa) * C4_ + cg];
    float4 aTR = fm[(rowT + rxa) * C4_ + cg];
    float4 aBL = fm[(rowB + lxa) * C4_ + cg];
    float4 aBR = fm[(rowB + rxa) * C4_ + cg];
    float4 bTL = fm[(rowT + lxb) * C4_ + cg];
    float4 bTR = fm[(rowT + rxb) * C4_ + cg];
    float4 bBL = fm[(rowB + lxb) * C4_ + cg];
    float4 bBR = fm[(rowB + rxb) * C4_ + cg];

    bool va = vy & vxa;
    bool vb = vy & vxb;

    float4 oa, ob;
    {
        float top, bot;
        top = aTL.x + (aTR.x - aTL.x) * xla;
        bot = aBL.x + (aBR.x - aBL.x) * xla;
        oa.x = top + (bot - top) * yl;
        top = aTL.y + (aTR.y - aTL.y) * xla;
        bot = aBL.y + (aBR.y - aBL.y) * xla;
        oa.y = top + (bot - top) * yl;
        top = aTL.z + (aTR.z - aTL.z) * xla;
        bot = aBL.z + (aBR.z - aBL.z) * xla;
        oa.z = top + (bot - top) * yl;
        top = aTL.w + (aTR.w - aTL.w) * xla;
        bot = aBL.w + (aBR.w - aBL.w) * xla;
        oa.w = top + (bot - top) * yl;

        top = bTL.x + (bTR.x - bTL.x) * xlb;
        bot = bBL.x + (bBR.x - bBL.x) * xlb;
        ob.x = top + (bot - top) * yl;
        top = bTL.y + (bTR.y - bTL.y) * xlb;
        bot = bBL.y + (bBR.y - bBL.y) * xlb;
        ob.y = top + (bot - top) * yl;
        top = bTL.z + (bTR.z - bTL.z) * xlb;
        bot = bBL.z + (bBR.z - bBL.z) * xlb;
        ob.z = top + (bot - top) * yl;
        top = bTL.w + (bTR.w - bTL.w) * xlb;
        bot = bBL.w + (bBR.w - bBL.w) * xlb;
        ob.w = top + (bot - top) * yl;
    }

    if (!va) { oa.x = 0.0f; oa.y = 0.0f; oa.z = 0.0f; oa.w = 0.0f; }
    if (!vb) { ob.x = 0.0f; ob.y = 0.0f; ob.z = 0.0f; ob.w = 0.0f; }

    size_t basepix = ((size_t)n * CH_ + i) * CW_;
    out[(basepix + j0)     * C4_ + cg] = oa;
    out[(basepix + j0 + 7) * C4_ + cg] = ob;
}

extern "C" void kernel_launch(void* const* d_in, const int* in_sizes, int n_in,
                              void* d_out, int out_size, void* d_ws, size_t ws_size,
                              hipStream_t stream) {
    const float4* fm   = (const float4*)d_in[0];
    const float*  rois = (const float*)d_in[1];
    float4*       out  = (float4*)d_out;

    // DIAGNOSTIC: two identical launches (idempotent). Second launch adds
    // exactly one kernel-duration to dur_us and, if the kernel is ~120us,
    // pushes it into the rocprof top-5 where its counters become visible.
    roi_crop_resize_kernel<<<BLOCKS_TOTAL, 256, 0, stream>>>(fm, rois, out);
    roi_crop_resize_kernel<<<BLOCKS_TOTAL, 256, 0, stream>>>(fm, rois, out);
}

// Round 5
// 265.329 us; speedup vs baseline: 1.1755x; 1.1755x over previous
//
#include <hip/hip_runtime.h>

// ROI crop_and_resize: feature_map [8,64,64,256] f32 NHWC, rois [8,128,4] f32
// out [1024,14,14,256] f32.
//
// v6: temporal-locality schedule. v5 diagnostic (double launch) measured the
// kernel at ~65 us vs a ~37 us compulsory-HBM floor (out 205.5 MB + fm 33.5
// MB) and a ~182 us fixed harness floor. Falsified so far: spatial XCD maps
// (x3), nt vs plain stores, marginal MLP. Untested: reuse DISTANCE. The 205
// MB store stream evicts an L2 line in ~10 us; previous schedules spread the
// 24.5x fm reuse across the whole batch timespan -> re-reads (822 MB) served
// from L3 (~50 us) instead of L2. This schedule makes reuse temporal:
//   block = one ROI (1024 blocks, 4 waves, ~25 iters of the v4 2-px body).
//   A ROI's ~240 KB fm footprint is read within one block over a few us ->
//   repeats hit L1/L2 before store-stream eviction.
// Keeps v4's 8-in-flight gather MLP and bit-identical per-pixel arithmetic.
// Single launch restored (v5's second launch was diagnostic only).

#define B_   8
#define H_   64
#define W_   64
#define C4_  64      // 256 channels / 4
#define NROI 128
#define CH_  14
#define CW_  14
// wave-task = (i, j0), j0 in [0,7): covers pixels (i,j0),(i,j0+7)
#define TASKS_PER_ROI (CH_ * 7)                 // 98
#define WAVES_PER_BLOCK 4
#define NBLOCKS (B_ * NROI)                     // 1024 = one block per roi

__global__ __launch_bounds__(256) void roi_crop_resize_kernel(
    const float4* __restrict__ fm,     // [8*64*64*64] float4
    const float*  __restrict__ rois,   // [1024*4]
    float4*       __restrict__ out)    // [200704*64] float4
{
    int tid = (int)threadIdx.x;
    int wid = tid >> 6;                 // wave id in block 0..3
    int cg  = tid & 63;                 // channel group (lane)
    int n   = (int)blockIdx.x;          // roi index 0..1023
    int b   = n >> 7;                   // batch

    // ---- hoisted per-roi state (amortized over ~25 iterations) ----
    const float* box = rois + n * 4;
    float y1 = box[0], x1 = box[1], y2 = box[2], x2 = box[3];

    const float Hm1 = (float)(H_ - 1);
    const float Wm1 = (float)(W_ - 1);

    float h_scale = (y2 - y1) * Hm1 / (float)(CH_ - 1);
    float w_scale = (x2 - x1) * Wm1 / (float)(CW_ - 1);

    size_t roibase = (size_t)n * (CH_ * CW_);   // first pixel of this roi

    for (int t = wid; t < TASKS_PER_ROI; t += WAVES_PER_BLOCK) {
        int i  = t / 7;                 // output row 0..13
        int j0 = t - i * 7;             // first column 0..6 (pair: j0, j0+7)

        // ---- shared y path (same i for both pixels) ----
        float in_y = y1 * Hm1 + (float)i * h_scale;
        bool  vy   = (in_y >= 0.0f) & (in_y <= Hm1);
        float fy   = floorf(in_y);
        float cy   = ceilf(in_y);
        int   ty   = (int)fminf(fmaxf(fy, 0.0f), Hm1);
        int   by   = (int)fminf(fmaxf(cy, 0.0f), Hm1);
        float yl   = in_y - fy;
        int rowT   = (b * H_ + ty) * W_;
        int rowB   = (b * H_ + by) * W_;

        // ---- x path, pixel A (j0) ----
        float in_xa = x1 * Wm1 + (float)j0 * w_scale;
        bool  vxa   = (in_xa >= 0.0f) & (in_xa <= Wm1);
        float fxa   = floorf(in_xa);
        float cxa   = ceilf(in_xa);
        int   lxa   = (int)fminf(fmaxf(fxa, 0.0f), Wm1);
        int   rxa   = (int)fminf(fmaxf(cxa, 0.0f), Wm1);
        float xla   = in_xa - fxa;

        // ---- x path, pixel B (j0+7) ----
        float in_xb = x1 * Wm1 + (float)(j0 + 7) * w_scale;
        bool  vxb   = (in_xb >= 0.0f) & (in_xb <= Wm1);
        float fxb   = floorf(in_xb);
        float cxb   = ceilf(in_xb);
        int   lxb   = (int)fminf(fmaxf(fxb, 0.0f), Wm1);
        int   rxb   = (int)fminf(fmaxf(cxb, 0.0f), Wm1);
        float xlb   = in_xb - fxb;

        // ---- 8 independent gather loads (max MLP) ----
        float4 aTL = fm[(rowT + lxa) * C4_ + cg];
        float4 aTR = fm[(rowT + rxa) * C4_ + cg];
        float4 aBL = fm[(rowB + lxa) * C4_ + cg];
        float4 aBR = fm[(rowB + rxa) * C4_ + cg];
        float4 bTL = fm[(rowT + lxb) * C4_ + cg];
        float4 bTR = fm[(rowT + rxb) * C4_ + cg];
        float4 bBL = fm[(rowB + lxb) * C4_ + cg];
        float4 bBR = fm[(rowB + rxb) * C4_ + cg];

        bool va = vy & vxa;
        bool vb = vy & vxb;

        float4 oa, ob;
        {
            float top, bot;
            top = aTL.x + (aTR.x - aTL.x) * xla;
            bot = aBL.x + (aBR.x - aBL.x) * xla;
            oa.x = top + (bot - top) * yl;
            top = aTL.y + (aTR.y - aTL.y) * xla;
            bot = aBL.y + (aBR.y - aBL.y) * xla;
            oa.y = top + (bot - top) * yl;
            top = aTL.z + (aTR.z - aTL.z) * xla;
            bot = aBL.z + (aBR.z - aBL.z) * xla;
            oa.z = top + (bot - top) * yl;
            top = aTL.w + (aTR.w - aTL.w) * xla;
            bot = aBL.w + (aBR.w - aBL.w) * xla;
            oa.w = top + (bot - top) * yl;

            top = bTL.x + (bTR.x - bTL.x) * xlb;
            bot = bBL.x + (bBR.x - bBL.x) * xlb;
            ob.x = top + (bot - top) * yl;
            top = bTL.y + (bTR.y - bTL.y) * xlb;
            bot = bBL.y + (bBR.y - bBL.y) * xlb;
            ob.y = top + (bot - top) * yl;
            top = bTL.z + (bTR.z - bTL.z) * xlb;
            bot = bBL.z + (bBR.z - bBL.z) * xlb;
            ob.z = top + (bot - top) * yl;
            top = bTL.w + (bTR.w - bTL.w) * xlb;
            bot = bBL.w + (bBR.w - bBL.w) * xlb;
            ob.w = top + (bot - top) * yl;
        }

        if (!va) { oa.x = 0.0f; oa.y = 0.0f; oa.z = 0.0f; oa.w = 0.0f; }
        if (!vb) { ob.x = 0.0f; ob.y = 0.0f; ob.z = 0.0f; ob.w = 0.0f; }

        size_t basepix = roibase + (size_t)i * CW_;
        out[(basepix + j0)     * C4_ + cg] = oa;
        out[(basepix + j0 + 7) * C4_ + cg] = ob;
    }
}

extern "C" void kernel_launch(void* const* d_in, const int* in_sizes, int n_in,
                              void* d_out, int out_size, void* d_ws, size_t ws_size,
                              hipStream_t stream) {
    const float4* fm   = (const float4*)d_in[0];
    const float*  rois = (const float*)d_in[1];
    float4*       out  = (float4*)d_out;

    roi_crop_resize_kernel<<<NBLOCKS, 256, 0, stream>>>(fm, rois, out);
}

// Round 6
// 249.866 us; speedup vs baseline: 1.2482x; 1.0619x over previous
//
#include <hip/hip_runtime.h>

// ROI crop_and_resize: feature_map [8,64,64,256] f32 NHWC, rois [8,128,4] f32
// out [1024,14,14,256] f32.
//
// v7: occupancy probe. Facts so far: kernel ~65us (v5 double-launch diag) vs
// ~37us compulsory HBM floor; insensitive to store path (v3) and to three
// read-locality maps (v1/v2); sensitive to wave-level parallelism (v6: fewer
// waves + per-iter vmcnt(0) serialization -> +28%). Never probed: occupancy.
// v4's 8 in-flight float4 loads (32 data VGPRs) + dual-pixel state almost
// certainly lands in the 65-128 VGPR band -> 4 waves/SIMD (occupancy halves
// at 64/128/256 VGPR). This version forces <=64 VGPR via __launch_bounds__
// (256 threads, min 8 waves/EU) -> 8 waves/SIMD resident, 2x in-flight
// loads and 2x wave-switch latency hiding. Body is bit-identical v4 math.
// If flat: occupancy isn't the lever and the gather is structurally
// L3-service-bound -> roofline call next round.

#define B_   8
#define H_   64
#define W_   64
#define C4_  64      // 256 channels / 4
#define NROI 128
#define CH_  14
#define CW_  14
// wave-task = (roi, i, j0) with j0 in [0,7): covers pixels (i,j0),(i,j0+7)
#define TASKS_PER_ROI (CH_ * 7)                 // 98
#define NTASKS (B_ * NROI * TASKS_PER_ROI)      // 100352
#define WAVES_PER_BLOCK 4
#define BLOCKS_TOTAL (NTASKS / WAVES_PER_BLOCK) // 25088

__global__ __launch_bounds__(256, 8) void roi_crop_resize_kernel(
    const float4* __restrict__ fm,     // [8*64*64*64] float4
    const float*  __restrict__ rois,   // [1024*4]
    float4*       __restrict__ out)    // [200704*64] float4
{
    int tid = (int)threadIdx.x;
    int wt  = (int)blockIdx.x * WAVES_PER_BLOCK + (tid >> 6);  // wave-task id
    int cg  = tid & 63;                                        // channel group

    int n  = wt / TASKS_PER_ROI;            // roi index 0..1023
    int t  = wt - n * TASKS_PER_ROI;
    int i  = t / 7;                         // output row 0..13
    int j0 = t - i * 7;                     // first column 0..6  (pair: j0, j0+7)
    int b  = n >> 7;                        // batch

    const float* box = rois + n * 4;
    float y1 = box[0], x1 = box[1], y2 = box[2], x2 = box[3];

    const float Hm1 = (float)(H_ - 1);
    const float Wm1 = (float)(W_ - 1);

    float h_scale = (y2 - y1) * Hm1 / (float)(CH_ - 1);
    float w_scale = (x2 - x1) * Wm1 / (float)(CW_ - 1);

    // ---- shared y path (same i for both pixels) ----
    float in_y = y1 * Hm1 + (float)i * h_scale;
    bool  vy   = (in_y >= 0.0f) & (in_y <= Hm1);
    float fy   = floorf(in_y);
    float cy   = ceilf(in_y);
    int   ty   = (int)fminf(fmaxf(fy, 0.0f), Hm1);
    int   by   = (int)fminf(fmaxf(cy, 0.0f), Hm1);
    float yl   = in_y - fy;
    int rowT   = (b * H_ + ty) * W_;
    int rowB   = (b * H_ + by) * W_;

    // ---- x path, pixel A (j0) ----
    float in_xa = x1 * Wm1 + (float)j0 * w_scale;
    bool  vxa   = (in_xa >= 0.0f) & (in_xa <= Wm1);
    float fxa   = floorf(in_xa);
    float cxa   = ceilf(in_xa);
    int   lxa   = (int)fminf(fmaxf(fxa, 0.0f), Wm1);
    int   rxa   = (int)fminf(fmaxf(cxa, 0.0f), Wm1);
    float xla   = in_xa - fxa;

    // ---- x path, pixel B (j0+7) ----
    float in_xb = x1 * Wm1 + (float)(j0 + 7) * w_scale;
    bool  vxb   = (in_xb >= 0.0f) & (in_xb <= Wm1);
    float fxb   = floorf(in_xb);
    float cxb   = ceilf(in_xb);
    int   lxb   = (int)fminf(fmaxf(fxb, 0.0f), Wm1);
    int   rxb   = (int)fminf(fmaxf(cxb, 0.0f), Wm1);
    float xlb   = in_xb - fxb;

    // ---- 32-bit element indices (helps allocator: 1 VGPR each + SGPR base) ----
    int iaTL = (rowT + lxa) * C4_ + cg;
    int iaTR = (rowT + rxa) * C4_ + cg;
    int iaBL = (rowB + lxa) * C4_ + cg;
    int iaBR = (rowB + rxa) * C4_ + cg;
    int ibTL = (rowT + lxb) * C4_ + cg;
    int ibTR = (rowT + rxb) * C4_ + cg;
    int ibBL = (rowB + lxb) * C4_ + cg;
    int ibBR = (rowB + rxb) * C4_ + cg;

    // ---- 8 independent gather loads (max MLP) ----
    float4 aTL = fm[iaTL];
    float4 aTR = fm[iaTR];
    float4 aBL = fm[iaBL];
    float4 aBR = fm[iaBR];
    float4 bTL = fm[ibTL];
    float4 bTR = fm[ibTR];
    float4 bBL = fm[ibBL];
    float4 bBR = fm[ibBR];

    bool va = vy & vxa;
    bool vb = vy & vxb;

    float4 oa, ob;
    {
        float top, bot;
        top = aTL.x + (aTR.x - aTL.x) * xla;
        bot = aBL.x + (aBR.x - aBL.x) * xla;
        oa.x = top + (bot - top) * yl;
        top = aTL.y + (aTR.y - aTL.y) * xla;
        bot = aBL.y + (aBR.y - aBL.y) * xla;
        oa.y = top + (bot - top) * yl;
        top = aTL.z + (aTR.z - aTL.z) * xla;
        bot = aBL.z + (aBR.z - aBL.z) * xla;
        oa.z = top + (bot - top) * yl;
        top = aTL.w + (aTR.w - aTL.w) * xla;
        bot = aBL.w + (aBR.w - aBL.w) * xla;
        oa.w = top + (bot - top) * yl;

        top = bTL.x + (bTR.x - bTL.x) * xlb;
        bot = bBL.x + (bBR.x - bBL.x) * xlb;
        ob.x = top + (bot - top) * yl;
        top = bTL.y + (bTR.y - bTL.y) * xlb;
        bot = bBL.y + (bBR.y - bBL.y) * xlb;
        ob.y = top + (bot - top) * yl;
        top = bTL.z + (bTR.z - bTL.z) * xlb;
        bot = bBL.z + (bBR.z - bBL.z) * xlb;
        ob.z = top + (bot - top) * yl;
        top = bTL.w + (bTR.w - bTL.w) * xlb;
        bot = bBL.w + (bBR.w - bBL.w) * xlb;
        ob.w = top + (bot - top) * yl;
    }

    if (!va) { oa.x = 0.0f; oa.y = 0.0f; oa.z = 0.0f; oa.w = 0.0f; }
    if (!vb) { ob.x = 0.0f; ob.y = 0.0f; ob.z = 0.0f; ob.w = 0.0f; }

    size_t basepix = ((size_t)n * CH_ + i) * CW_;
    out[(basepix + j0)     * C4_ + cg] = oa;
    out[(basepix + j0 + 7) * C4_ + cg] = ob;
}

extern "C" void kernel_launch(void* const* d_in, const int* in_sizes, int n_in,
                              void* d_out, int out_size, void* d_ws, size_t ws_size,
                              hipStream_t stream) {
    const float4* fm   = (const float4*)d_in[0];
    const float*  rois = (const float*)d_in[1];
    float4*       out  = (float4*)d_out;

    roi_crop_resize_kernel<<<BLOCKS_TOTAL, 256, 0, stream>>>(fm, rois, out);
}

// Round 7
// 248.144 us; speedup vs baseline: 1.2569x; 1.0069x over previous
//
#include <hip/hip_runtime.h>

// ROI crop_and_resize: feature_map [8,64,64,256] f32 NHWC, rois [8,128,4] f32
// out [1024,14,14,256] f32.
//
// v8 = v4 restored (best measured: 247.06 us). Session ledger:
//   kernel ~65us (measured via idempotent double-launch diagnostic, v5)
//   vs ~37us compulsory HBM floor (out 205.5MB + cold fm 33.5MB @ 6.6TB/s,
//   rate validated by the harness's own 822MB/123us fill);
//   ~182us of dur_us is fixed harness cost (poison fill + overhead).
// Levers tested, all <=1% except where noted:
//   - nt vs plain stores: flat          - 3 read-locality XCD maps: flat
//   - per-wave MLP x2 (this kernel): -0.8%
//   - block=ROI temporal locality: +7% WORSE (TLP loss; occupancy matters)
//   - forced <=64 VGPR occupancy: flat (v4 already at 8 waves/SIMD cap)
// Conclusion: latency/service-bound gather (822MB cache-served reads, 24.5x
// reuse) overlapped with a saturated store drain, at max occupancy and max
// useful per-wave MLP. Remaining ~28us slack has no surviving theory.
//
// Structure: wave-task = (roi, i, j0): one wave computes output pixels
// (i,j0) and (i,j0+7) across all 256 channels; 8 independent float4 gather
// loads in flight; shared y-path math; plain float4 stores.

#define B_   8
#define H_   64
#define W_   64
#define C4_  64      // 256 channels / 4
#define NROI 128
#define CH_  14
#define CW_  14
// wave-task = (roi, i, j0) with j0 in [0,7): covers pixels (i,j0),(i,j0+7)
#define TASKS_PER_ROI (CH_ * 7)                 // 98
#define NTASKS (B_ * NROI * TASKS_PER_ROI)      // 100352
#define WAVES_PER_BLOCK 4
#define BLOCKS_TOTAL (NTASKS / WAVES_PER_BLOCK) // 25088

__global__ __launch_bounds__(256) void roi_crop_resize_kernel(
    const float4* __restrict__ fm,     // [8*64*64*64] float4
    const float*  __restrict__ rois,   // [1024*4]
    float4*       __restrict__ out)    // [200704*64] float4
{
    int tid = (int)threadIdx.x;
    int wt  = (int)blockIdx.x * WAVES_PER_BLOCK + (tid >> 6);  // wave-task id
    int cg  = tid & 63;                                        // channel group

    int n  = wt / TASKS_PER_ROI;            // roi index 0..1023
    int t  = wt - n * TASKS_PER_ROI;
    int i  = t / 7;                         // output row 0..13
    int j0 = t - i * 7;                     // first column 0..6  (pair: j0, j0+7)
    int b  = n >> 7;                        // batch

    const float* box = rois + n * 4;
    float y1 = box[0], x1 = box[1], y2 = box[2], x2 = box[3];

    const float Hm1 = (float)(H_ - 1);
    const float Wm1 = (float)(W_ - 1);

    float h_scale = (y2 - y1) * Hm1 / (float)(CH_ - 1);
    float w_scale = (x2 - x1) * Wm1 / (float)(CW_ - 1);

    // ---- shared y path (same i for both pixels) ----
    float in_y = y1 * Hm1 + (float)i * h_scale;
    bool  vy   = (in_y >= 0.0f) & (in_y <= Hm1);
    float fy   = floorf(in_y);
    float cy   = ceilf(in_y);
    int   ty   = (int)fminf(fmaxf(fy, 0.0f), Hm1);
    int   by   = (int)fminf(fmaxf(cy, 0.0f), Hm1);
    float yl   = in_y - fy;
    int rowT   = (b * H_ + ty) * W_;
    int rowB   = (b * H_ + by) * W_;

    // ---- x path, pixel A (j0) ----
    float in_xa = x1 * Wm1 + (float)j0 * w_scale;
    bool  vxa   = (in_xa >= 0.0f) & (in_xa <= Wm1);
    float fxa   = floorf(in_xa);
    float cxa   = ceilf(in_xa);
    int   lxa   = (int)fminf(fmaxf(fxa, 0.0f), Wm1);
    int   rxa   = (int)fminf(fmaxf(cxa, 0.0f), Wm1);
    float xla   = in_xa - fxa;

    // ---- x path, pixel B (j0+7) ----
    float in_xb = x1 * Wm1 + (float)(j0 + 7) * w_scale;
    bool  vxb   = (in_xb >= 0.0f) & (in_xb <= Wm1);
    float fxb   = floorf(in_xb);
    float cxb   = ceilf(in_xb);
    int   lxb   = (int)fminf(fmaxf(fxb, 0.0f), Wm1);
    int   rxb   = (int)fminf(fmaxf(cxb, 0.0f), Wm1);
    float xlb   = in_xb - fxb;

    // ---- 8 independent gather loads (max MLP) ----
    float4 aTL = fm[(rowT + lxa) * C4_ + cg];
    float4 aTR = fm[(rowT + rxa) * C4_ + cg];
    float4 aBL = fm[(rowB + lxa) * C4_ + cg];
    float4 aBR = fm[(rowB + rxa) * C4_ + cg];
    float4 bTL = fm[(rowT + lxb) * C4_ + cg];
    float4 bTR = fm[(rowT + rxb) * C4_ + cg];
    float4 bBL = fm[(rowB + lxb) * C4_ + cg];
    float4 bBR = fm[(rowB + rxb) * C4_ + cg];

    bool va = vy & vxa;
    bool vb = vy & vxb;

    float4 oa, ob;
    {
        float top, bot;
        top = aTL.x + (aTR.x - aTL.x) * xla;
        bot = aBL.x + (aBR.x - aBL.x) * xla;
        oa.x = top + (bot - top) * yl;
        top = aTL.y + (aTR.y - aTL.y) * xla;
        bot = aBL.y + (aBR.y - aBL.y) * xla;
        oa.y = top + (bot - top) * yl;
        top = aTL.z + (aTR.z - aTL.z) * xla;
        bot = aBL.z + (aBR.z - aBL.z) * xla;
        oa.z = top + (bot - top) * yl;
        top = aTL.w + (aTR.w - aTL.w) * xla;
        bot = aBL.w + (aBR.w - aBL.w) * xla;
        oa.w = top + (bot - top) * yl;

        top = bTL.x + (bTR.x - bTL.x) * xlb;
        bot = bBL.x + (bBR.x - bBL.x) * xlb;
        ob.x = top + (bot - top) * yl;
        top = bTL.y + (bTR.y - bTL.y) * xlb;
        bot = bBL.y + (bBR.y - bBL.y) * xlb;
        ob.y = top + (bot - top) * yl;
        top = bTL.z + (bTR.z - bTL.z) * xlb;
        bot = bBL.z + (bBR.z - bBL.z) * xlb;
        ob.z = top + (bot - top) * yl;
        top = bTL.w + (bTR.w - bTL.w) * xlb;
        bot = bBL.w + (bBR.w - bBL.w) * xlb;
        ob.w = top + (bot - top) * yl;
    }

    if (!va) { oa.x = 0.0f; oa.y = 0.0f; oa.z = 0.0f; oa.w = 0.0f; }
    if (!vb) { ob.x = 0.0f; ob.y = 0.0f; ob.z = 0.0f; ob.w = 0.0f; }

    size_t basepix = ((size_t)n * CH_ + i) * CW_;
    out[(basepix + j0)     * C4_ + cg] = oa;
    out[(basepix + j0 + 7) * C4_ + cg] = ob;
}

extern "C" void kernel_launch(void* const* d_in, const int* in_sizes, int n_in,
                              void* d_out, int out_size, void* d_ws, size_t ws_size,
                              hipStream_t stream) {
    const float4* fm   = (const float4*)d_in[0];
    const float*  rois = (const float*)d_in[1];
    float4*       out  = (float4*)d_out;

    roi_crop_resize_kernel<<<BLOCKS_TOTAL, 256, 0, stream>>>(fm, rois, out);
}